// Round 1
// baseline (1798.908 us; speedup 1.0000x reference)
//
#include <hip/hip_runtime.h>

#define NA   256   // anchors
#define CIN  128
#define HFD  320
#define IMGD 1280
#define OCG  8     // out channels per block
#define NGRP 32    // 256/OCG

__global__ __launch_bounds__(256) void zero_ws_kernel(float* logits, float* out) {
    int i = blockIdx.x * 256 + threadIdx.x;
    if (i < NA * 1024) logits[i] = 0.0f;
    if (i == 0) out[0] = 0.0f;
}

// One block = one anchor x 8 output channels of conv1.
// conv1 (3x3, SAME on the 32x32 crop, zero pad) -> relu -> conv2 partial
// (linear in channels) -> atomicAdd into per-anchor logits.
__global__ __launch_bounds__(256) void conv_fused_kernel(
    const float* __restrict__ fm, const int* __restrict__ anchors,
    const float* __restrict__ W1, const float* __restrict__ b1,
    const float* __restrict__ W2, float* __restrict__ logits)
{
    const int g = blockIdx.x;          // channel group 0..31
    const int n = blockIdx.y;          // anchor
    const int t = threadIdx.x;
    const int y0 = anchors[n * 4 + 2]; // starts = anchors[:, [2,0]] = (row, col)
    const int x0 = anchors[n * 4 + 0];

    __shared__ float s_in[34 * 36];          // zero-padded crop channel
    __shared__ float s_h[OCG][34 * 36];      // zero-padded relu(h) for this group

    for (int i = t; i < 34 * 36; i += 256) s_in[i] = 0.0f;
    for (int i = t; i < OCG * 34 * 36; i += 256) ((float*)s_h)[i] = 0.0f;

    float acc[4][OCG];
    #pragma unroll
    for (int r = 0; r < 4; ++r)
        #pragma unroll
        for (int o = 0; o < OCG; ++o) acc[r][o] = 0.0f;

    for (int c = 0; c < CIN; ++c) {
        __syncthreads();
        const float* src = fm + (size_t)c * HFD * HFD;
        #pragma unroll
        for (int r = 0; r < 4; ++r) {
            int idx = t + r * 256;
            int i = idx >> 5, j = idx & 31;
            s_in[(i + 1) * 36 + (j + 1)] = src[(y0 + i) * HFD + x0 + j];
        }
        __syncthreads();

        // neighborhoods into registers (wave reads are stride-1: 2-way bank alias, free)
        float nb[4][9];
        #pragma unroll
        for (int r = 0; r < 4; ++r) {
            int p = t + r * 256;
            int i = p >> 5, j = p & 31;
            #pragma unroll
            for (int ky = 0; ky < 3; ++ky)
                #pragma unroll
                for (int kx = 0; kx < 3; ++kx)
                    nb[r][ky * 3 + kx] = s_in[(i + ky) * 36 + j + kx];
        }
        // weights are block-uniform -> s_load (scalar cache), no LDS traffic
        #pragma unroll
        for (int o = 0; o < OCG; ++o) {
            const float* __restrict__ wp = W1 + ((size_t)(g * OCG + o) * CIN + c) * 9;
            float w0 = wp[0], w1 = wp[1], w2 = wp[2], w3 = wp[3], w4 = wp[4];
            float w5 = wp[5], w6 = wp[6], w7 = wp[7], w8 = wp[8];
            #pragma unroll
            for (int r = 0; r < 4; ++r) {
                float a0 = acc[r][o];
                a0 = fmaf(nb[r][0], w0, a0);
                a0 = fmaf(nb[r][1], w1, a0);
                a0 = fmaf(nb[r][2], w2, a0);
                a0 = fmaf(nb[r][3], w3, a0);
                a0 = fmaf(nb[r][4], w4, a0);
                a0 = fmaf(nb[r][5], w5, a0);
                a0 = fmaf(nb[r][6], w6, a0);
                a0 = fmaf(nb[r][7], w7, a0);
                a0 = fmaf(nb[r][8], w8, a0);
                acc[r][o] = a0;
            }
        }
    }

    __syncthreads();
    #pragma unroll
    for (int r = 0; r < 4; ++r) {
        int p = t + r * 256;
        int i = p >> 5, j = p & 31;
        #pragma unroll
        for (int o = 0; o < OCG; ++o)
            s_h[o][(i + 1) * 36 + j + 1] = fmaxf(acc[r][o] + b1[g * OCG + o], 0.0f);
    }
    __syncthreads();

    // conv2 partial for this channel group (SAME on 32x32 h, zero pad)
    #pragma unroll
    for (int r = 0; r < 4; ++r) {
        int p = t + r * 256;
        int i = p >> 5, j = p & 31;
        float part = 0.0f;
        #pragma unroll
        for (int o = 0; o < OCG; ++o) {
            const float* __restrict__ wp2 = W2 + (size_t)(g * OCG + o) * 9;
            #pragma unroll
            for (int ky = 0; ky < 3; ++ky)
                #pragma unroll
                for (int kx = 0; kx < 3; ++kx)
                    part = fmaf(s_h[o][(i + ky) * 36 + j + kx], wp2[ky * 3 + kx], part);
        }
        atomicAdd(&logits[n * 1024 + p], part);
    }
}

__global__ __launch_bounds__(256) void bce_reduce_kernel(
    const float* __restrict__ logits, const int* __restrict__ seg,
    const int* __restrict__ anchors, const int* __restrict__ labels,
    const int* __restrict__ base_classes, const float* __restrict__ b2,
    float* __restrict__ out)
{
    const int n = blockIdx.x;
    const int t = threadIdx.x;
    const int y0 = anchors[n * 4 + 2];
    const int x0 = anchors[n * 4 + 0];
    const int tgt_cls = base_classes[labels[n]];
    const float bias2 = b2[0];

    float lsum = 0.0f;
    #pragma unroll
    for (int r = 0; r < 4; ++r) {
        int p = t + r * 256;
        int i = p >> 5, j = p & 31;
        float l = logits[n * 1024 + p] + bias2;
        // mask = seg[4h][4w]; tgt = (mask == tgt_cls) -- exact int compare
        int sv = seg[(size_t)(4 * (y0 + i)) * IMGD + 4 * (x0 + j)];
        float tgt = (sv == tgt_cls) ? 1.0f : 0.0f;
        float bce = fmaxf(l, 0.0f) - l * tgt + log1pf(expf(-fabsf(l)));
        lsum += bce;
    }
    #pragma unroll
    for (int off = 32; off > 0; off >>= 1) lsum += __shfl_down(lsum, off, 64);
    __shared__ float s[4];
    if ((t & 63) == 0) s[t >> 6] = lsum;
    __syncthreads();
    if (t == 0) {
        float tot = s[0] + s[1] + s[2] + s[3];
        // mean over 1024 px, then sum/(N+1e-10)
        const float scale = 1.0f / (1024.0f * (256.0f + 1e-10f));
        atomicAdd(out, tot * scale);
    }
}

extern "C" void kernel_launch(void* const* d_in, const int* in_sizes, int n_in,
                              void* d_out, int out_size, void* d_ws, size_t ws_size,
                              hipStream_t stream) {
    const float* fm           = (const float*)d_in[0];
    const int*   seg          = (const int*)d_in[1];
    const int*   anchors      = (const int*)d_in[2];
    const int*   labels       = (const int*)d_in[3];
    const int*   base_classes = (const int*)d_in[4];
    const float* W1           = (const float*)d_in[5];
    const float* b1           = (const float*)d_in[6];
    const float* W2           = (const float*)d_in[7];
    const float* b2           = (const float*)d_in[8];
    float* out    = (float*)d_out;
    float* logits = (float*)d_ws;   // NA*1024 floats

    zero_ws_kernel<<<(NA * 1024 + 255) / 256, 256, 0, stream>>>(logits, out);
    conv_fused_kernel<<<dim3(NGRP, NA), 256, 0, stream>>>(fm, anchors, W1, b1, W2, logits);
    bce_reduce_kernel<<<NA, 256, 0, stream>>>(logits, seg, anchors, labels, base_classes, b2, out);
}

// Round 2
// 642.225 us; speedup vs baseline: 2.8011x; 2.8011x over previous
//
#include <hip/hip_runtime.h>

typedef __attribute__((ext_vector_type(8))) short short8;
typedef __attribute__((ext_vector_type(16))) float floatx16;
typedef unsigned short ushort_t;
typedef unsigned int uint_t;

#define NA   256
#define CIN  128
#define HFD  320
#define FMPX (HFD*HFD)
#define IMGD 1280

// ws layout (bytes): [0,1MB) logits f32; then w1r bf16 [9][256][128]; then w2r bf16 [32][256]
#define W1R_BYTE_OFF (1u<<20)
#define W2R_BYTE_OFF ((1u<<20) + 9*256*128*2)

__device__ __forceinline__ ushort_t f2bf(float v) {
    // round-to-nearest (ties up) — bias negligible, 2 VALU ops
    uint_t u = __float_as_uint(v);
    return (ushort_t)((u + 0x8000u) >> 16);
}

__global__ __launch_bounds__(256) void prep_kernel(
    const float* __restrict__ W1, const float* __restrict__ W2,
    float* __restrict__ logits, float* __restrict__ out,
    ushort_t* __restrict__ w1r, ushort_t* __restrict__ w2r)
{
    const int b = blockIdx.x, t = threadIdx.x;
    if (b < 1024) {
        logits[b * 256 + t] = 0.0f;                     // NA*1024 floats
    } else if (b < 1024 + 128) {
        int e = (b - 1024) * 256 + t;                   // 32768 (oc,cin) pairs
        int oc = e >> 7, cin = e & 127;
        #pragma unroll
        for (int tap = 0; tap < 9; ++tap)
            w1r[(tap * 256 + oc) * 128 + cin] = f2bf(W1[(oc * 128 + cin) * 9 + tap]);
    } else {
        #pragma unroll
        for (int i = 0; i < 32; ++i) {
            int e = i * 256 + t;                        // [32 tap-rows][256 oc]
            int nrow = e >> 8, oc = e & 255;
            w2r[nrow * 256 + oc] = f2bf(nrow < 9 ? W2[oc * 9 + nrow] : 0.0f);
        }
        if (t == 0) out[0] = 0.0f;
    }
}

// Block = (anchor, row-half 16 rows, 64-oc group). 4 waves; wave w owns rows 4w..4w+3.
// Wave tile: 4 m-tiles (each = one crop row, M=32 cols) x 2 n-tiles (32 oc) on 32x32x16 bf16 MFMA.
// K-loop: 8 cin-chunks of 16 x 9 taps. A staged in LDS [18 pad-rows][34 pad-cols][16 cin] bf16.
// Epilogue: relu(h+b1) -> LDS -> v_tap = h @ W2^T (MFMA, N=32 taps, 9 valid) -> scatter-add.
__global__ __launch_bounds__(256, 2) void conv_mfma_kernel(
    const float* __restrict__ fm, const int* __restrict__ anchors,
    const ushort_t* __restrict__ w1r, const ushort_t* __restrict__ w2r,
    const float* __restrict__ b1, float* __restrict__ logits)
{
    const int gh   = blockIdx.x;       // 0..7
    const int g    = gh >> 1;          // oc group (64 oc)
    const int half = gh & 1;
    const int n    = blockIdx.y;       // anchor
    const int t    = threadIdx.x;
    const int w    = t >> 6;
    const int lane = t & 63;
    const int l31  = lane & 31;
    const int kh   = lane >> 5;        // k-half selector (k = kh*8 + j)

    const int x0 = anchors[n * 4 + 0];
    const int y0 = anchors[n * 4 + 2];
    const int r0 = half * 16;

    __shared__ __align__(16) ushort_t s_a[18 * 34 * 16]; // [pr][pc][cin16]
    __shared__ __align__(16) ushort_t s_h[16 * 32 * 32]; // [lr][col][oc32]
    __shared__ float s_log[18 * 32];

    floatx16 acc[4][2];
    #pragma unroll
    for (int mt = 0; mt < 4; ++mt)
        #pragma unroll
        for (int nt = 0; nt < 2; ++nt)
            #pragma unroll
            for (int r = 0; r < 16; ++r) acc[mt][nt][r] = 0.0f;

    for (int chunk = 0; chunk < 8; ++chunk) {
        const int cbase = chunk * 16;
        __syncthreads();
        // ---- stage padded crop chunk: fp32 -> bf16 pairs (cin-adjacent pack) ----
        #pragma unroll
        for (int i = 0; i < 18; ++i) {          // 18*256 = 18 rows * 8 cpairs * 32 cols
            int e   = t + 256 * i;
            int pc  = e & 31;                   // padded col 0..31 (cc = pc-1)
            int q   = e >> 5;
            int cp  = q & 7;
            int pr  = q >> 3;                   // 0..17
            int cr  = r0 + pr - 1;
            int cc  = pc - 1;
            int c   = cbase + 2 * cp;
            bool valid = ((unsigned)cr < 32u) && (cc >= 0);
            const float* src = fm + (size_t)c * FMPX + (y0 + cr) * HFD + (x0 + cc);
            float v0 = valid ? src[0]    : 0.0f;
            float v1 = valid ? src[FMPX] : 0.0f;
            uint_t packed = (uint_t)f2bf(v0) | ((uint_t)f2bf(v1) << 16);
            *(uint_t*)&s_a[(pr * 34 + pc) * 16 + 2 * cp] = packed;
        }
        #pragma unroll
        for (int i = 0; i < 2; ++i) {           // cols pc=32,33 (cc=31 valid, cc=32 zero)
            int e = t + 256 * i;
            if (e < 288) {
                int pc = 32 + (e & 1);
                int q  = e >> 1;
                int cp = q & 7, pr = q >> 3;
                int cr = r0 + pr - 1, cc = pc - 1;
                int c  = cbase + 2 * cp;
                bool valid = ((unsigned)cr < 32u) && (cc < 32);
                const float* src = fm + (size_t)c * FMPX + (y0 + cr) * HFD + (x0 + cc);
                float v0 = valid ? src[0]    : 0.0f;
                float v1 = valid ? src[FMPX] : 0.0f;
                uint_t packed = (uint_t)f2bf(v0) | ((uint_t)f2bf(v1) << 16);
                *(uint_t*)&s_a[(pr * 34 + pc) * 16 + 2 * cp] = packed;
            }
        }
        __syncthreads();
        // ---- MFMA over 9 taps ----
        #pragma unroll
        for (int tap = 0; tap < 9; ++tap) {
            const int ky = tap / 3, kx = tap % 3;
            short8 bfrag[2];
            #pragma unroll
            for (int nt = 0; nt < 2; ++nt) {
                int oc = g * 64 + nt * 32 + l31;                  // B: n = lane&31
                bfrag[nt] = *(const short8*)&w1r[(tap * 256 + oc) * 128 + cbase + kh * 8];
            }
            #pragma unroll
            for (int mt = 0; mt < 4; ++mt) {
                int pr = 4 * w + mt + ky;                          // padded row
                int pc = l31 + kx;                                 // A: m = lane&31 = crop col
                short8 afrag = *(const short8*)&s_a[(pr * 34 + pc) * 16 + kh * 8];
                acc[mt][0] = __builtin_amdgcn_mfma_f32_32x32x16_bf16(afrag, bfrag[0], acc[mt][0], 0, 0, 0);
                acc[mt][1] = __builtin_amdgcn_mfma_f32_32x32x16_bf16(afrag, bfrag[1], acc[mt][1], 0, 0, 0);
            }
        }
    }

    // ---- epilogue: relu(h+b1) -> LDS; v_tap = h @ W2^T via MFMA (2 oc-half passes) ----
    floatx16 vacc[4];
    #pragma unroll
    for (int mt = 0; mt < 4; ++mt)
        #pragma unroll
        for (int r = 0; r < 16; ++r) vacc[mt][r] = 0.0f;

    const float bias0 = b1[g * 64 + l31];
    const float bias1 = b1[g * 64 + 32 + l31];

    #pragma unroll
    for (int pass = 0; pass < 2; ++pass) {
        __syncthreads();
        float bias = pass ? bias1 : bias0;
        #pragma unroll
        for (int mt = 0; mt < 4; ++mt) {
            int lr = 4 * w + mt;
            #pragma unroll
            for (int reg = 0; reg < 16; ++reg) {
                // C layout (m74/m101): col(n=oc) = lane&31, row(m=crop col) = (reg&3)+8*(reg>>2)+4*kh
                int ccol = (reg & 3) + 8 * (reg >> 2) + 4 * kh;
                float hv = fmaxf(acc[mt][pass][reg] + bias, 0.0f);
                s_h[(lr * 32 + ccol) * 32 + l31] = f2bf(hv);
            }
        }
        __syncthreads();
        #pragma unroll
        for (int ks = 0; ks < 2; ++ks) {
            int ocg = g * 64 + pass * 32 + ks * 16 + kh * 8;
            short8 bw = *(const short8*)&w2r[l31 * 256 + ocg];     // B[k=oc][n=tap]
            #pragma unroll
            for (int mt = 0; mt < 4; ++mt) {
                int lr = 4 * w + mt;
                short8 ah = *(const short8*)&s_h[(lr * 32 + l31) * 32 + ks * 16 + kh * 8];
                vacc[mt] = __builtin_amdgcn_mfma_f32_32x32x16_bf16(ah, bw, vacc[mt], 0, 0, 0);
            }
        }
    }

    // ---- scatter v_tap into per-block logits tile (rows r0-1..r0+16), then global atomics ----
    __syncthreads();
    for (int i = t; i < 18 * 32; i += 256) s_log[i] = 0.0f;
    __syncthreads();
    {
        int tap = l31;
        if (tap < 9) {
            int ky = tap / 3, kx = tap - ky * 3;
            #pragma unroll
            for (int mt = 0; mt < 4; ++mt) {
                int outr = 4 * w + mt + 2 - ky;        // index into 18-row tile
                #pragma unroll
                for (int reg = 0; reg < 16; ++reg) {
                    int qcol = (reg & 3) + 8 * (reg >> 2) + 4 * kh;
                    int outc = qcol + 1 - kx;
                    if (outc >= 0 && outc < 32)
                        atomicAdd(&s_log[outr * 32 + outc], vacc[mt][reg]);
                }
            }
        }
    }
    __syncthreads();
    for (int i = t; i < 18 * 32; i += 256) {
        int outr = i >> 5, outc = i & 31;
        int R = r0 + outr - 1;
        if ((unsigned)R < 32u)
            atomicAdd(&logits[n * 1024 + R * 32 + outc], s_log[i]);
    }
}

__global__ __launch_bounds__(256) void bce_reduce_kernel(
    const float* __restrict__ logits, const int* __restrict__ seg,
    const int* __restrict__ anchors, const int* __restrict__ labels,
    const int* __restrict__ base_classes, const float* __restrict__ b2,
    float* __restrict__ out)
{
    const int n = blockIdx.x;
    const int t = threadIdx.x;
    const int y0 = anchors[n * 4 + 2];
    const int x0 = anchors[n * 4 + 0];
    const int tgt_cls = base_classes[labels[n]];
    const float bias2 = b2[0];

    float lsum = 0.0f;
    #pragma unroll
    for (int r = 0; r < 4; ++r) {
        int p = t + r * 256;
        int i = p >> 5, j = p & 31;
        float l = logits[n * 1024 + p] + bias2;
        int sv = seg[(size_t)(4 * (y0 + i)) * IMGD + 4 * (x0 + j)];
        float tgt = (sv == tgt_cls) ? 1.0f : 0.0f;
        lsum += fmaxf(l, 0.0f) - l * tgt + log1pf(expf(-fabsf(l)));
    }
    #pragma unroll
    for (int off = 32; off > 0; off >>= 1) lsum += __shfl_down(lsum, off, 64);
    __shared__ float s[4];
    if ((t & 63) == 0) s[t >> 6] = lsum;
    __syncthreads();
    if (t == 0) {
        float tot = s[0] + s[1] + s[2] + s[3];
        const float scale = 1.0f / (1024.0f * (256.0f + 1e-10f));
        atomicAdd(out, tot * scale);
    }
}

extern "C" void kernel_launch(void* const* d_in, const int* in_sizes, int n_in,
                              void* d_out, int out_size, void* d_ws, size_t ws_size,
                              hipStream_t stream) {
    const float* fm           = (const float*)d_in[0];
    const int*   seg          = (const int*)d_in[1];
    const int*   anchors      = (const int*)d_in[2];
    const int*   labels       = (const int*)d_in[3];
    const int*   base_classes = (const int*)d_in[4];
    const float* W1           = (const float*)d_in[5];
    const float* b1           = (const float*)d_in[6];
    const float* W2           = (const float*)d_in[7];
    const float* b2           = (const float*)d_in[8];
    float* out = (float*)d_out;

    float*    logits = (float*)d_ws;
    ushort_t* w1r    = (ushort_t*)((char*)d_ws + W1R_BYTE_OFF);
    ushort_t* w2r    = (ushort_t*)((char*)d_ws + W2R_BYTE_OFF);

    prep_kernel<<<1024 + 128 + 1, 256, 0, stream>>>(W1, W2, logits, out, w1r, w2r);
    conv_mfma_kernel<<<dim3(8, NA), 256, 0, stream>>>(fm, anchors, w1r, w2r, b1, logits);
    bce_reduce_kernel<<<NA, 256, 0, stream>>>(logits, seg, anchors, labels, base_classes, b2, out);
}

// Round 3
// 613.282 us; speedup vs baseline: 2.9332x; 1.0472x over previous
//
#include <hip/hip_runtime.h>

typedef __attribute__((ext_vector_type(8))) short short8;
typedef __attribute__((ext_vector_type(16))) float floatx16;
typedef unsigned short ushort_t;
typedef unsigned int uint_t;

#define NA   256
#define CIN  128
#define HFD  320
#define FMPX (HFD*HFD)
#define IMGD 1280

// ws layout (bytes): [0,1MB) logits f32; then w1r bf16 [9][256][128]; then w2r bf16 [32][256]
#define W1R_BYTE_OFF (1u<<20)
#define W2R_BYTE_OFF ((1u<<20) + 9*256*128*2)

#define PSTR_A 2720   // elements per cin-octet plane of s_a (10*34*8)
#define PSTR_H 2056   // elements per oc-octet plane of s_h (8*32*8 + 8 pad -> bank offset 4)

__device__ __forceinline__ ushort_t f2bf(float v) {
    uint_t u = __float_as_uint(v);
    return (ushort_t)((u + 0x8000u) >> 16);
}

__global__ __launch_bounds__(256) void prep_kernel(
    const float* __restrict__ W1, const float* __restrict__ W2,
    float* __restrict__ logits, float* __restrict__ out,
    ushort_t* __restrict__ w1r, ushort_t* __restrict__ w2r)
{
    const int b = blockIdx.x, t = threadIdx.x;
    if (b < 1024) {
        logits[b * 256 + t] = 0.0f;
    } else if (b < 1024 + 128) {
        int e = (b - 1024) * 256 + t;
        int oc = e >> 7, cin = e & 127;
        #pragma unroll
        for (int tap = 0; tap < 9; ++tap)
            w1r[(tap * 256 + oc) * 128 + cin] = f2bf(W1[(oc * 128 + cin) * 9 + tap]);
    } else {
        #pragma unroll
        for (int i = 0; i < 32; ++i) {
            int e = i * 256 + t;
            int nrow = e >> 8, oc = e & 255;
            w2r[nrow * 256 + oc] = f2bf(nrow < 9 ? W2[oc * 9 + nrow] : 0.0f);
        }
        if (t == 0) out[0] = 0.0f;
    }
}

// Block = (anchor, 8-row quarter, 64-oc group); 4096 blocks, XCD-swizzled so all
// 16 blocks of one anchor land on one XCD (crop shared via that XCD's L2).
// Wave w owns rows 2w..2w+1 (mt=2) x 64 oc (nt=2) on 32x32x16 bf16 MFMA.
// s_a: [cin-octet 2][10 pad-rows][34 pad-cols][8 cin] -> A-reads lane-stride 16B, conflict-free.
// A-frags register-cached across ky: 12 ds_read_b128 feed 36 MFMAs per wave-chunk.
// B (w1r) read straight from global (L1/L2-hot). Epilogue: relu(h+b1) -> s_h (union with s_a)
// -> v_tap = h @ W2^T via MFMA -> scatter-add (LDS then global atomics).
__global__ __launch_bounds__(256, 3) void conv_mfma_kernel(
    const float* __restrict__ fm, const int* __restrict__ anchors,
    const ushort_t* __restrict__ w1r, const ushort_t* __restrict__ w2r,
    const float* __restrict__ b1, float* __restrict__ logits)
{
    const int id  = blockIdx.x;
    const int xcd = id & 7, sid = id >> 3;
    const int n   = xcd * 32 + (sid >> 4);
    const int q   = (sid >> 2) & 3;
    const int g   = sid & 3;

    const int t    = threadIdx.x;
    const int w    = t >> 6;
    const int lane = t & 63;
    const int l31  = lane & 31;
    const int kh   = lane >> 5;

    const int x0 = anchors[n * 4 + 0];
    const int y0 = anchors[n * 4 + 2];
    const int r0 = q * 8;

    __shared__ __align__(16) char smem[4 * PSTR_H * 2];  // 16448 B: s_a (10880) U s_h
    ushort_t* s_a = (ushort_t*)smem;
    ushort_t* s_h = (ushort_t*)smem;
    __shared__ float s_log[10 * 32];

    const int pc_b = t & 31;   // staging body col
    const int cp   = t >> 5;   // staging cin-pair 0..7

    floatx16 acc[2][2];
    #pragma unroll
    for (int mt = 0; mt < 2; ++mt)
        #pragma unroll
        for (int nt = 0; nt < 2; ++nt)
            #pragma unroll
            for (int r = 0; r < 16; ++r) acc[mt][nt][r] = 0.0f;

    for (int chunk = 0; chunk < 8; ++chunk) {
        const int cbase = chunk * 16;
        __syncthreads();
        // ---- stage 10 pad-rows x 34 pad-cols x 16 cin (fp32 -> bf16 pairs) ----
        {
            const int cc = pc_b - 1;
            const float* base = fm + (size_t)(cbase + 2 * cp) * FMPX + x0 + cc;
            #pragma unroll
            for (int pr = 0; pr < 10; ++pr) {
                int cr = r0 + pr - 1;
                bool valid = ((unsigned)cr < 32u) && (cc >= 0);
                const float* src = base + (y0 + cr) * HFD;
                float v0 = valid ? src[0]    : 0.0f;
                float v1 = valid ? src[FMPX] : 0.0f;
                uint_t packed = (uint_t)f2bf(v0) | ((uint_t)f2bf(v1) << 16);
                *(uint_t*)&s_a[(cp >> 2) * PSTR_A + (pr * 34 + pc_b) * 8 + (cp & 3) * 2] = packed;
            }
            if (t < 160) {  // pad cols pc=32 (cc=31 valid), pc=33 (zero)
                int pc  = 32 + (t & 1);
                int cp2 = (t >> 1) & 7;
                int pr  = t >> 4;
                int cr  = r0 + pr - 1;
                int c2  = pc - 1;
                bool valid = ((unsigned)cr < 32u) && (c2 < 32);
                const float* src = fm + (size_t)(cbase + 2 * cp2) * FMPX + (y0 + cr) * HFD + (x0 + c2);
                float v0 = valid ? src[0]    : 0.0f;
                float v1 = valid ? src[FMPX] : 0.0f;
                uint_t packed = (uint_t)f2bf(v0) | ((uint_t)f2bf(v1) << 16);
                *(uint_t*)&s_a[(cp2 >> 2) * PSTR_A + (pr * 34 + pc) * 8 + (cp2 & 3) * 2] = packed;
            }
        }
        __syncthreads();
        // ---- MFMA: 3 kx x (4 A-frags reg-cached) x 3 ky x 2 mt x 2 nt ----
        #pragma unroll
        for (int kx = 0; kx < 3; ++kx) {
            short8 bfrag[3][2];
            #pragma unroll
            for (int ky = 0; ky < 3; ++ky)
                #pragma unroll
                for (int nt = 0; nt < 2; ++nt) {
                    int oc = g * 64 + nt * 32 + l31;
                    bfrag[ky][nt] = *(const short8*)&w1r[((ky * 3 + kx) * 256 + oc) * 128 + cbase + kh * 8];
                }
            short8 afrag[4];
            #pragma unroll
            for (int idx = 0; idx < 4; ++idx) {
                int pr = 2 * w + idx;
                afrag[idx] = *(const short8*)&s_a[kh * PSTR_A + (pr * 34 + l31 + kx) * 8];
            }
            #pragma unroll
            for (int ky = 0; ky < 3; ++ky)
                #pragma unroll
                for (int mt = 0; mt < 2; ++mt) {
                    acc[mt][0] = __builtin_amdgcn_mfma_f32_32x32x16_bf16(afrag[mt + ky], bfrag[ky][0], acc[mt][0], 0, 0, 0);
                    acc[mt][1] = __builtin_amdgcn_mfma_f32_32x32x16_bf16(afrag[mt + ky], bfrag[ky][1], acc[mt][1], 0, 0, 0);
                }
        }
    }

    // ---- epilogue: relu(h+b1) -> s_h; v_tap = h @ W2^T (2 oc-half passes) ----
    floatx16 vacc[2];
    #pragma unroll
    for (int mt = 0; mt < 2; ++mt)
        #pragma unroll
        for (int r = 0; r < 16; ++r) vacc[mt][r] = 0.0f;

    #pragma unroll
    for (int pass = 0; pass < 2; ++pass) {
        __syncthreads();
        float bias = b1[g * 64 + pass * 32 + l31];
        #pragma unroll
        for (int mt = 0; mt < 2; ++mt) {
            int lr = 2 * w + mt;
            #pragma unroll
            for (int reg = 0; reg < 16; ++reg) {
                int col = (reg & 3) + 8 * (reg >> 2) + 4 * kh;  // C: m = crop col
                float hv = fmaxf(acc[mt][pass][reg] + bias, 0.0f);
                s_h[(l31 >> 3) * PSTR_H + (lr * 32 + col) * 8 + (l31 & 7)] = f2bf(hv);
            }
        }
        __syncthreads();
        #pragma unroll
        for (int ks = 0; ks < 2; ++ks) {
            short8 bw = *(const short8*)&w2r[l31 * 256 + g * 64 + pass * 32 + ks * 16 + kh * 8];
            #pragma unroll
            for (int mt = 0; mt < 2; ++mt) {
                int lr = 2 * w + mt;
                short8 ah = *(const short8*)&s_h[(ks * 2 + kh) * PSTR_H + (lr * 32 + l31) * 8];
                vacc[mt] = __builtin_amdgcn_mfma_f32_32x32x16_bf16(ah, bw, vacc[mt], 0, 0, 0);
            }
        }
    }

    // ---- scatter v_tap into 10x32 tile, then global atomics ----
    __syncthreads();
    for (int i = t; i < 10 * 32; i += 256) s_log[i] = 0.0f;
    __syncthreads();
    if (l31 < 9) {
        int ky = l31 / 3, kx = l31 - ky * 3;
        #pragma unroll
        for (int mt = 0; mt < 2; ++mt) {
            int outr = 2 * w + mt + 2 - ky;   // tile row, R = r0 + outr - 1
            #pragma unroll
            for (int reg = 0; reg < 16; ++reg) {
                int col  = (reg & 3) + 8 * (reg >> 2) + 4 * kh;
                int outc = col + 1 - kx;
                if (outc >= 0 && outc < 32)
                    atomicAdd(&s_log[outr * 32 + outc], vacc[mt][reg]);
            }
        }
    }
    __syncthreads();
    for (int i = t; i < 10 * 32; i += 256) {
        int outr = i >> 5, outc = i & 31;
        int R = r0 + outr - 1;
        if ((unsigned)R < 32u)
            atomicAdd(&logits[n * 1024 + R * 32 + outc], s_log[i]);
    }
}

__global__ __launch_bounds__(256) void bce_reduce_kernel(
    const float* __restrict__ logits, const int* __restrict__ seg,
    const int* __restrict__ anchors, const int* __restrict__ labels,
    const int* __restrict__ base_classes, const float* __restrict__ b2,
    float* __restrict__ out)
{
    const int n = blockIdx.x;
    const int t = threadIdx.x;
    const int y0 = anchors[n * 4 + 2];
    const int x0 = anchors[n * 4 + 0];
    const int tgt_cls = base_classes[labels[n]];
    const float bias2 = b2[0];

    float lsum = 0.0f;
    #pragma unroll
    for (int r = 0; r < 4; ++r) {
        int p = t + r * 256;
        int i = p >> 5, j = p & 31;
        float l = logits[n * 1024 + p] + bias2;
        int sv = seg[(size_t)(4 * (y0 + i)) * IMGD + 4 * (x0 + j)];
        float tgt = (sv == tgt_cls) ? 1.0f : 0.0f;
        lsum += fmaxf(l, 0.0f) - l * tgt + log1pf(expf(-fabsf(l)));
    }
    #pragma unroll
    for (int off = 32; off > 0; off >>= 1) lsum += __shfl_down(lsum, off, 64);
    __shared__ float s[4];
    if ((t & 63) == 0) s[t >> 6] = lsum;
    __syncthreads();
    if (t == 0) {
        float tot = s[0] + s[1] + s[2] + s[3];
        const float scale = 1.0f / (1024.0f * (256.0f + 1e-10f));
        atomicAdd(out, tot * scale);
    }
}

extern "C" void kernel_launch(void* const* d_in, const int* in_sizes, int n_in,
                              void* d_out, int out_size, void* d_ws, size_t ws_size,
                              hipStream_t stream) {
    const float* fm           = (const float*)d_in[0];
    const int*   seg          = (const int*)d_in[1];
    const int*   anchors      = (const int*)d_in[2];
    const int*   labels       = (const int*)d_in[3];
    const int*   base_classes = (const int*)d_in[4];
    const float* W1           = (const float*)d_in[5];
    const float* b1           = (const float*)d_in[6];
    const float* W2           = (const float*)d_in[7];
    const float* b2           = (const float*)d_in[8];
    float* out = (float*)d_out;

    float*    logits = (float*)d_ws;
    ushort_t* w1r    = (ushort_t*)((char*)d_ws + W1R_BYTE_OFF);
    ushort_t* w2r    = (ushort_t*)((char*)d_ws + W2R_BYTE_OFF);

    prep_kernel<<<1024 + 128 + 1, 256, 0, stream>>>(W1, W2, logits, out, w1r, w2r);
    conv_mfma_kernel<<<4096, 256, 0, stream>>>(fm, anchors, w1r, w2r, b1, logits);
    bce_reduce_kernel<<<NA, 256, 0, stream>>>(logits, seg, anchors, labels, base_classes, b2, out);
}

// Round 4
// 379.530 us; speedup vs baseline: 4.7398x; 1.6159x over previous
//
#include <hip/hip_runtime.h>

typedef __attribute__((ext_vector_type(8))) short short8;
typedef __attribute__((ext_vector_type(16))) float floatx16;
typedef unsigned short ushort_t;
typedef unsigned int uint_t;

#define NA   256
#define CIN  128
#define HFD  320
#define FMPX (HFD*HFD)
#define IMGD 1280

// ws layout (bytes): [0,1MB) logits f32; then w1r bf16 [9][256][128]; then w2r bf16 [32][256]
#define W1R_BYTE_OFF (1u<<20)
#define W2R_BYTE_OFF ((1u<<20) + 9*256*128*2)

#define PSTR_A 4896            // elems per cin-octet plane of s_a: 18*34*8
#define SB_OFF (2*PSTR_A)      // s_b starts after s_a (9792 elems)
#define PSTR_H 4096            // 16*32*8 elems per oc-octet plane of s_h

__device__ __forceinline__ ushort_t f2bf(float v) {
    uint_t u = __float_as_uint(v);
    return (ushort_t)((u + 0x8000u) >> 16);
}

__global__ __launch_bounds__(256) void prep_kernel(
    const float* __restrict__ W1, const float* __restrict__ W2,
    float* __restrict__ logits, float* __restrict__ out,
    ushort_t* __restrict__ w1r, ushort_t* __restrict__ w2r)
{
    const int b = blockIdx.x, t = threadIdx.x;
    if (b < 1024) {
        logits[b * 256 + t] = 0.0f;
    } else if (b < 1024 + 128) {
        int e = (b - 1024) * 256 + t;
        int oc = e >> 7, cin = e & 127;
        #pragma unroll
        for (int tap = 0; tap < 9; ++tap)
            w1r[(tap * 256 + oc) * 128 + cin] = f2bf(W1[(oc * 128 + cin) * 9 + tap]);
    } else {
        #pragma unroll
        for (int i = 0; i < 32; ++i) {
            int e = i * 256 + t;
            int nrow = e >> 8, oc = e & 255;
            w2r[nrow * 256 + oc] = f2bf(nrow < 9 ? W2[oc * 9 + nrow] : 0.0f);
        }
        if (t == 0) out[0] = 0.0f;
    }
}

// Block = (anchor, 16-row half, 64-oc group); grid 2048, XCD-swizzled (8 blocks/anchor per XCD).
// Wave w owns output rows 4w..4w+3 (4 m-tiles of one 32-px row) x 64 oc (2 n-tiles).
// Per chunk (16 cin): A in s_a [2 kh][18 pr][34 pc][8 cin] (pads zeroed ONCE, chunk-invariant),
// B in s_b [9 tap][2 kh][64 oc][8 cin]. Software pipeline: issue next chunk's global loads to
// REGISTERS before the MFMA section (latency covered), write regs->LDS after the barrier.
// MFMA loop reads LDS only: per kx, 6 B-frags + 6 A-frags (ky-shared) feed 24 MFMAs.
__global__ __launch_bounds__(256, 2) void conv_mfma_kernel(
    const float* __restrict__ fm, const int* __restrict__ anchors,
    const ushort_t* __restrict__ w1r, const ushort_t* __restrict__ w2r,
    const float* __restrict__ b1, float* __restrict__ logits)
{
    const int id   = blockIdx.x;
    const int xcd  = id & 7, sid = id >> 3;
    const int n    = xcd * 32 + (sid >> 3);
    const int rem  = sid & 7;
    const int half = rem >> 2;
    const int g    = rem & 3;

    const int t    = threadIdx.x;
    const int w    = t >> 6;
    const int lane = t & 63;
    const int l31  = lane & 31;
    const int kh   = lane >> 5;

    const int x0 = anchors[n * 4 + 0];
    const int y0 = anchors[n * 4 + 2];
    const int r0 = half * 16;

    __shared__ __align__(16) char smem[(2 * PSTR_A + 9216) * 2];   // 38016 B: s_a | s_b ; union s_h
    ushort_t* s_a = (ushort_t*)smem;
    ushort_t* s_b = s_a + SB_OFF;
    ushort_t* s_h = (ushort_t*)smem;
    __shared__ float s_log[18 * 32];

    // staging mapping: thread = (cin-pair cp, body col pc_b); body rows pr=1..16, one halo row
    const int cp   = t >> 5;
    const int pc_b = t & 31;
    const int pr_h = half ? 0 : 17;          // halo pad-row that holds real data
    const int cr_h = half ? 15 : 16;         // its crop row

    // zero s_a once: pad cols pc{0,33} and pad rows pr{0,17} stay zero across all chunks
    for (int i = t; i < 2 * PSTR_A / 2; i += 256) ((uint_t*)s_a)[i] = 0u;

    floatx16 acc[4][2];
    #pragma unroll
    for (int mt = 0; mt < 4; ++mt)
        #pragma unroll
        for (int nt = 0; nt < 2; ++nt)
            #pragma unroll
            for (int r = 0; r < 16; ++r) acc[mt][nt][r] = 0.0f;

    float pa0[17], pa1[17];
    uint4 pb[5];

    #define ISSUE_AB(cbase)                                                          \
    {                                                                                \
        const float* abase = fm + (size_t)((cbase) + 2 * cp) * FMPX + x0 + pc_b;     \
        _Pragma("unroll")                                                            \
        for (int i = 0; i < 16; ++i) {                                               \
            const float* s = abase + (y0 + r0 + i) * HFD;                            \
            pa0[i] = s[0]; pa1[i] = s[FMPX];                                         \
        }                                                                            \
        { const float* s = abase + (y0 + cr_h) * HFD; pa0[16] = s[0]; pa1[16] = s[FMPX]; } \
        _Pragma("unroll")                                                            \
        for (int j = 0; j < 5; ++j) {                                                \
            int slot = t + 256 * j; if (slot >= 1152) slot -= 1152;                  \
            int tap = slot >> 7, rr = slot & 127, oc = rr >> 1, khb = rr & 1;        \
            pb[j] = *(const uint4*)&w1r[(tap * 256 + g * 64 + oc) * 128 + (cbase) + khb * 8]; \
        }                                                                            \
    }

    #define WRITE_AB()                                                               \
    {                                                                                \
        _Pragma("unroll")                                                            \
        for (int i = 0; i < 17; ++i) {                                               \
            int pr = (i < 16) ? (1 + i) : pr_h;                                      \
            uint_t packed = (uint_t)f2bf(pa0[i]) | ((uint_t)f2bf(pa1[i]) << 16);     \
            *(uint_t*)&s_a[(cp >> 2) * PSTR_A + (pr * 34 + pc_b + 1) * 8 + (cp & 3) * 2] = packed; \
        }                                                                            \
        _Pragma("unroll")                                                            \
        for (int j = 0; j < 5; ++j) {                                                \
            int slot = t + 256 * j; if (slot >= 1152) slot -= 1152;                  \
            int tap = slot >> 7, rr = slot & 127, oc = rr >> 1, khb = rr & 1;        \
            *(uint4*)&s_b[((tap * 2 + khb) * 64 + oc) * 8] = pb[j];                  \
        }                                                                            \
    }

    ISSUE_AB(0);
    __syncthreads();            // zero-fill visible before staging writes
    WRITE_AB();
    __syncthreads();

    for (int chunk = 0; chunk < 8; ++chunk) {
        if (chunk < 7) ISSUE_AB((chunk + 1) * 16);   // fire-and-forget; lands during MFMA
        #pragma unroll
        for (int kx = 0; kx < 3; ++kx) {
            short8 bfrag[3][2];
            #pragma unroll
            for (int ky = 0; ky < 3; ++ky)
                #pragma unroll
                for (int nt = 0; nt < 2; ++nt)
                    bfrag[ky][nt] = *(const short8*)&s_b[(((ky * 3 + kx) * 2 + kh) * 64 + nt * 32 + l31) * 8];
            short8 afrag[6];
            #pragma unroll
            for (int idx = 0; idx < 6; ++idx)
                afrag[idx] = *(const short8*)&s_a[kh * PSTR_A + ((4 * w + idx) * 34 + l31 + kx) * 8];
            #pragma unroll
            for (int ky = 0; ky < 3; ++ky)
                #pragma unroll
                for (int mt = 0; mt < 4; ++mt) {
                    acc[mt][0] = __builtin_amdgcn_mfma_f32_32x32x16_bf16(afrag[mt + ky], bfrag[ky][0], acc[mt][0], 0, 0, 0);
                    acc[mt][1] = __builtin_amdgcn_mfma_f32_32x32x16_bf16(afrag[mt + ky], bfrag[ky][1], acc[mt][1], 0, 0, 0);
                }
        }
        __syncthreads();                      // waves done reading; prefetch loads already landed
        if (chunk < 7) { WRITE_AB(); __syncthreads(); }
    }

    // ---- epilogue: relu(h+b1) -> s_h (union); v_tap = h @ W2^T (2 oc-half passes) ----
    floatx16 vacc[4];
    #pragma unroll
    for (int mt = 0; mt < 4; ++mt)
        #pragma unroll
        for (int r = 0; r < 16; ++r) vacc[mt][r] = 0.0f;

    #pragma unroll
    for (int pass = 0; pass < 2; ++pass) {
        __syncthreads();
        float bias = b1[g * 64 + pass * 32 + l31];
        #pragma unroll
        for (int mt = 0; mt < 4; ++mt) {
            int lr = 4 * w + mt;
            #pragma unroll
            for (int reg = 0; reg < 16; ++reg) {
                int col = (reg & 3) + 8 * (reg >> 2) + 4 * kh;   // C: m = crop col
                float hv = fmaxf(acc[mt][pass][reg] + bias, 0.0f);
                s_h[(l31 >> 3) * PSTR_H + (lr * 32 + col) * 8 + (l31 & 7)] = f2bf(hv);
            }
        }
        __syncthreads();
        #pragma unroll
        for (int ks = 0; ks < 2; ++ks) {
            short8 bw = *(const short8*)&w2r[l31 * 256 + g * 64 + pass * 32 + ks * 16 + kh * 8];
            #pragma unroll
            for (int mt = 0; mt < 4; ++mt) {
                int lr = 4 * w + mt;
                short8 ah = *(const short8*)&s_h[(ks * 2 + kh) * PSTR_H + (lr * 32 + l31) * 8];
                vacc[mt] = __builtin_amdgcn_mfma_f32_32x32x16_bf16(ah, bw, vacc[mt], 0, 0, 0);
            }
        }
    }

    // ---- scatter v_tap into 18x32 tile, then global atomics ----
    __syncthreads();
    for (int i = t; i < 18 * 32; i += 256) s_log[i] = 0.0f;
    __syncthreads();
    if (l31 < 9) {
        int ky = l31 / 3, kx = l31 - ky * 3;
        #pragma unroll
        for (int mt = 0; mt < 4; ++mt) {
            int outr = 4 * w + mt + 2 - ky;       // tile row; R = r0 + outr - 1
            #pragma unroll
            for (int reg = 0; reg < 16; ++reg) {
                int col  = (reg & 3) + 8 * (reg >> 2) + 4 * kh;
                int outc = col + 1 - kx;
                if (outc >= 0 && outc < 32)
                    atomicAdd(&s_log[outr * 32 + outc], vacc[mt][reg]);
            }
        }
    }
    __syncthreads();
    for (int i = t; i < 18 * 32; i += 256) {
        int outr = i >> 5, outc = i & 31;
        int R = r0 + outr - 1;
        if ((unsigned)R < 32u)
            atomicAdd(&logits[n * 1024 + R * 32 + outc], s_log[i]);
    }
}

__global__ __launch_bounds__(256) void bce_reduce_kernel(
    const float* __restrict__ logits, const int* __restrict__ seg,
    const int* __restrict__ anchors, const int* __restrict__ labels,
    const int* __restrict__ base_classes, const float* __restrict__ b2,
    float* __restrict__ out)
{
    const int n = blockIdx.x;
    const int t = threadIdx.x;
    const int y0 = anchors[n * 4 + 2];
    const int x0 = anchors[n * 4 + 0];
    const int tgt_cls = base_classes[labels[n]];
    const float bias2 = b2[0];

    float lsum = 0.0f;
    #pragma unroll
    for (int r = 0; r < 4; ++r) {
        int p = t + r * 256;
        int i = p >> 5, j = p & 31;
        float l = logits[n * 1024 + p] + bias2;
        int sv = seg[(size_t)(4 * (y0 + i)) * IMGD + 4 * (x0 + j)];
        float tgt = (sv == tgt_cls) ? 1.0f : 0.0f;
        lsum += fmaxf(l, 0.0f) - l * tgt + log1pf(expf(-fabsf(l)));
    }
    #pragma unroll
    for (int off = 32; off > 0; off >>= 1) lsum += __shfl_down(lsum, off, 64);
    __shared__ float s[4];
    if ((t & 63) == 0) s[t >> 6] = lsum;
    __syncthreads();
    if (t == 0) {
        float tot = s[0] + s[1] + s[2] + s[3];
        const float scale = 1.0f / (1024.0f * (256.0f + 1e-10f));
        atomicAdd(out, tot * scale);
    }
}

extern "C" void kernel_launch(void* const* d_in, const int* in_sizes, int n_in,
                              void* d_out, int out_size, void* d_ws, size_t ws_size,
                              hipStream_t stream) {
    const float* fm           = (const float*)d_in[0];
    const int*   seg          = (const int*)d_in[1];
    const int*   anchors      = (const int*)d_in[2];
    const int*   labels       = (const int*)d_in[3];
    const int*   base_classes = (const int*)d_in[4];
    const float* W1           = (const float*)d_in[5];
    const float* b1           = (const float*)d_in[6];
    const float* W2           = (const float*)d_in[7];
    const float* b2           = (const float*)d_in[8];
    float* out = (float*)d_out;

    float*    logits = (float*)d_ws;
    ushort_t* w1r    = (ushort_t*)((char*)d_ws + W1R_BYTE_OFF);
    ushort_t* w2r    = (ushort_t*)((char*)d_ws + W2R_BYTE_OFF);

    prep_kernel<<<1024 + 128 + 1, 256, 0, stream>>>(W1, W2, logits, out, w1r, w2r);
    conv_mfma_kernel<<<2048, 256, 0, stream>>>(fm, anchors, w1r, w2r, b1, logits);
    bce_reduce_kernel<<<NA, 256, 0, stream>>>(logits, seg, anchors, labels, base_classes, b2, out);
}

// Round 5
// 340.590 us; speedup vs baseline: 5.2817x; 1.1143x over previous
//
#include <hip/hip_runtime.h>

typedef __attribute__((ext_vector_type(8))) short short8;
typedef __attribute__((ext_vector_type(16))) float floatx16;
typedef unsigned short ushort_t;
typedef unsigned int uint_t;
typedef unsigned char uchar_t;
typedef long long i64_t;

#define NA   256
#define CIN  128
#define HFD  320
#define FMPX (HFD*HFD)
#define IMGD 1280

// ws layout (bytes):
//   [0, 1MB)              logits f32 (NA*1024)
//   [1MB, 1MB+294912)     w1r fp8  [9 tap][256 oc][128 cin], scaled x64
//   [+294912, +311296)    w2r bf16 [32 krow][256 oc]
//   [2MB, 2MB+13107200)   fmT fp8  [320 y][320 x][128 c]
#define W1R_BYTE_OFF (1u<<20)
#define W2R_BYTE_OFF ((1u<<20) + 9*256*128)
#define FMT_BYTE_OFF (2u<<20)

#define SA_BYTES (18*34*16)              // 9792
#define SB_BYTES (9*64*16)               // 9216
#define BUF_BYTES (SA_BYTES + SB_BYTES)  // 19008
#define PSTR_H 4096                      // 16*32*8 elems per oc-octet plane of s_h (bf16)

__device__ __forceinline__ ushort_t f2bf(float v) {
    uint_t u = __float_as_uint(v);
    return (ushort_t)((u + 0x8000u) >> 16);
}
__device__ __forceinline__ uchar_t f2fp8(float v) {
    int r = __builtin_amdgcn_cvt_pk_fp8_f32(v, 0.0f, 0, false);
    return (uchar_t)(r & 0xff);
}

__global__ __launch_bounds__(256) void prep_misc(
    const float* __restrict__ W1, const float* __restrict__ W2,
    float* __restrict__ logits, float* __restrict__ out,
    uchar_t* __restrict__ w1r, ushort_t* __restrict__ w2r)
{
    const int b = blockIdx.x, t = threadIdx.x;
    if (b < 1024) {
        logits[b * 256 + t] = 0.0f;
    } else if (b < 1024 + 128) {
        int e = (b - 1024) * 256 + t;
        int oc = e >> 7, cin = e & 127;
        #pragma unroll
        for (int tap = 0; tap < 9; ++tap)
            w1r[(tap * 256 + oc) * 128 + cin] = f2fp8(W1[(oc * 128 + cin) * 9 + tap] * 64.0f);
    } else {
        #pragma unroll
        for (int i = 0; i < 32; ++i) {
            int e = i * 256 + t;
            int nrow = e >> 8, oc = e & 255;
            w2r[nrow * 256 + oc] = f2bf(nrow < 9 ? W2[oc * 9 + nrow] : 0.0f);
        }
        if (t == 0) out[0] = 0.0f;
    }
}

// fm f32 [c][y][x] -> fmT fp8 [y][x][c] (channels-last: 16B at (y,x) = 16 consecutive cin)
__global__ __launch_bounds__(256) void prep_transpose(
    const float* __restrict__ fm, uchar_t* __restrict__ fmT)
{
    __shared__ uchar_t s[32 * 144];
    const int t = threadIdx.x;
    const int y = blockIdx.y, x0b = blockIdx.x * 32;
    #pragma unroll
    for (int i = 0; i < 16; ++i) {
        int e = t + 256 * i;
        int c = e >> 5, xo = e & 31;
        s[xo * 144 + c] = f2fp8(fm[(size_t)c * FMPX + y * HFD + x0b + xo]);
    }
    __syncthreads();
    {
        int xo = t >> 3, cg = t & 7;
        uint4 v = *(const uint4*)&s[xo * 144 + cg * 16];
        *(uint4*)&fmT[((size_t)(y * HFD + x0b + xo)) * 128 + cg * 16] = v;
    }
}

// Block = (anchor, 16-row half, 64-oc group); grid 2048, XCD-swizzled.
// Wave w owns output rows 4w..4w+3 x 64 oc (2 n-tiles) on 32x32x16 fp8_fp8 MFMA.
// Double-buffered LDS (s_a 18x34x16 fp8 | s_b 9x64x16 fp8), ONE barrier per chunk:
// issue next chunk's global loads (24 VGPRs, no spill), MFMA on buf[c&1], write buf[(c+1)&1].
// Pads of both buffers zeroed once (chunk-invariant). Epilogue in bf16 as before (acc/64).
__global__ __launch_bounds__(256, 2) void conv_mfma_kernel(
    const float* __restrict__ fm, const int* __restrict__ anchors,
    const uchar_t* __restrict__ fmT, const uchar_t* __restrict__ w1r,
    const ushort_t* __restrict__ w2r, const float* __restrict__ b1,
    float* __restrict__ logits)
{
    const int id   = blockIdx.x;
    const int xcd  = id & 7, sid = id >> 3;
    const int n    = xcd * 32 + (sid >> 3);
    const int rem  = sid & 7;
    const int half = rem >> 2;
    const int g    = rem & 3;

    const int t    = threadIdx.x;
    const int w    = t >> 6;
    const int lane = t & 63;
    const int l31  = lane & 31;
    const int kh   = lane >> 5;

    const int x0 = anchors[n * 4 + 0];
    const int y0 = anchors[n * 4 + 2];
    const int r0 = half * 16;
    const int pro = 1 - half;          // pad-row offset of first real row

    __shared__ __align__(16) char smem[2 * BUF_BYTES];   // 38016 B; union s_h (32768 B)
    ushort_t* s_h = (ushort_t*)smem;
    __shared__ float s_log[18 * 32];

    // zero both buffers once (pads stay zero across chunks; interiors overwritten)
    for (int i = t; i < 2 * BUF_BYTES / 4; i += 256) ((uint_t*)smem)[i] = 0u;

    floatx16 acc[4][2];
    #pragma unroll
    for (int mt = 0; mt < 4; ++mt)
        #pragma unroll
        for (int nt = 0; nt < 2; ++nt)
            #pragma unroll
            for (int r = 0; r < 16; ++r) acc[mt][nt][r] = 0.0f;

    uint4 pa[3], pb[3];

    // A: 544 cells (17 real rows x 32 cols) of 16B; B: 576 slots (9 tap x 64 oc) of 16B
    #define ISSUE_AB(cbase)                                                               \
    {                                                                                     \
        _Pragma("unroll")                                                                 \
        for (int j = 0; j < 3; ++j) {                                                     \
            int e = t + 256 * j;                                                          \
            if (j < 2 || e < 544) {                                                       \
                int ri = e >> 5, col = e & 31;                                            \
                int pr = ri + pro, cr = r0 - 1 + pr;                                      \
                pa[j] = *(const uint4*)&fmT[((size_t)((y0 + cr) * HFD + x0 + col)) * 128 + (cbase)]; \
            }                                                                             \
        }                                                                                 \
        _Pragma("unroll")                                                                 \
        for (int j = 0; j < 3; ++j) {                                                     \
            int e = t + 256 * j;                                                          \
            if (j < 2 || e < 576) {                                                       \
                int tap = e >> 6, oc = e & 63;                                            \
                pb[j] = *(const uint4*)&w1r[(size_t)((tap * 256 + g * 64 + oc) * 128) + (cbase)]; \
            }                                                                             \
        }                                                                                 \
    }

    #define WRITE_AB(bufc)                                                                \
    {                                                                                     \
        char* ba = smem + (bufc) * BUF_BYTES;                                             \
        char* bb = ba + SA_BYTES;                                                         \
        _Pragma("unroll")                                                                 \
        for (int j = 0; j < 3; ++j) {                                                     \
            int e = t + 256 * j;                                                          \
            if (j < 2 || e < 544) {                                                       \
                int ri = e >> 5, col = e & 31;                                            \
                int pr = ri + pro;                                                        \
                *(uint4*)(ba + (pr * 34 + col + 1) * 16) = pa[j];                         \
            }                                                                             \
        }                                                                                 \
        _Pragma("unroll")                                                                 \
        for (int j = 0; j < 3; ++j) {                                                     \
            int e = t + 256 * j;                                                          \
            if (j < 2 || e < 576) {                                                       \
                int tap = e >> 6, oc = e & 63;                                            \
                *(uint4*)(bb + (tap * 64 + oc) * 16) = pb[j];                             \
            }                                                                             \
        }                                                                                 \
    }

    ISSUE_AB(0);
    __syncthreads();            // zero-fill visible
    WRITE_AB(0);
    __syncthreads();

    for (int chunk = 0; chunk < 8; ++chunk) {
        if (chunk < 7) ISSUE_AB((chunk + 1) * 16);
        const char* ba = smem + (chunk & 1) * BUF_BYTES;
        const char* bb = ba + SA_BYTES;
        #pragma unroll
        for (int kx = 0; kx < 3; ++kx) {
            i64_t bfrag[3][2];
            #pragma unroll
            for (int ky = 0; ky < 3; ++ky)
                #pragma unroll
                for (int nt = 0; nt < 2; ++nt)
                    bfrag[ky][nt] = *(const i64_t*)(bb + ((ky * 3 + kx) * 64 + nt * 32 + l31) * 16 + kh * 8);
            i64_t afrag[6];
            #pragma unroll
            for (int idx = 0; idx < 6; ++idx)
                afrag[idx] = *(const i64_t*)(ba + ((4 * w + idx) * 34 + l31 + kx) * 16 + kh * 8);
            #pragma unroll
            for (int ky = 0; ky < 3; ++ky)
                #pragma unroll
                for (int mt = 0; mt < 4; ++mt) {
                    acc[mt][0] = __builtin_amdgcn_mfma_f32_32x32x16_fp8_fp8(afrag[mt + ky], bfrag[ky][0], acc[mt][0], 0, 0, 0);
                    acc[mt][1] = __builtin_amdgcn_mfma_f32_32x32x16_fp8_fp8(afrag[mt + ky], bfrag[ky][1], acc[mt][1], 0, 0, 0);
                }
        }
        if (chunk < 7) WRITE_AB((chunk + 1) & 1);
        __syncthreads();
    }

    // ---- epilogue: h = acc/64 + b1, relu -> s_h (bf16, union); v_tap = h @ W2^T ----
    floatx16 vacc[4];
    #pragma unroll
    for (int mt = 0; mt < 4; ++mt)
        #pragma unroll
        for (int r = 0; r < 16; ++r) vacc[mt][r] = 0.0f;

    #pragma unroll
    for (int pass = 0; pass < 2; ++pass) {
        __syncthreads();
        float bias = b1[g * 64 + pass * 32 + l31];
        #pragma unroll
        for (int mt = 0; mt < 4; ++mt) {
            int lr = 4 * w + mt;
            #pragma unroll
            for (int reg = 0; reg < 16; ++reg) {
                int col = (reg & 3) + 8 * (reg >> 2) + 4 * kh;   // C: m = crop col
                float hv = fmaxf(acc[mt][pass][reg] * 0.015625f + bias, 0.0f);
                s_h[(l31 >> 3) * PSTR_H + (lr * 32 + col) * 8 + (l31 & 7)] = f2bf(hv);
            }
        }
        __syncthreads();
        #pragma unroll
        for (int ks = 0; ks < 2; ++ks) {
            short8 bw = *(const short8*)&w2r[l31 * 256 + g * 64 + pass * 32 + ks * 16 + kh * 8];
            #pragma unroll
            for (int mt = 0; mt < 4; ++mt) {
                int lr = 4 * w + mt;
                short8 ah = *(const short8*)&s_h[(ks * 2 + kh) * PSTR_H + (lr * 32 + l31) * 8];
                vacc[mt] = __builtin_amdgcn_mfma_f32_32x32x16_bf16(ah, bw, vacc[mt], 0, 0, 0);
            }
        }
    }

    // ---- scatter v_tap into 18x32 tile, then global atomics ----
    __syncthreads();
    for (int i = t; i < 18 * 32; i += 256) s_log[i] = 0.0f;
    __syncthreads();
    if (l31 < 9) {
        int ky = l31 / 3, kx = l31 - ky * 3;
        #pragma unroll
        for (int mt = 0; mt < 4; ++mt) {
            int outr = 4 * w + mt + 2 - ky;       // tile row; R = r0 + outr - 1
            #pragma unroll
            for (int reg = 0; reg < 16; ++reg) {
                int col  = (reg & 3) + 8 * (reg >> 2) + 4 * kh;
                int outc = col + 1 - kx;
                if (outc >= 0 && outc < 32)
                    atomicAdd(&s_log[outr * 32 + outc], vacc[mt][reg]);
            }
        }
    }
    __syncthreads();
    for (int i = t; i < 18 * 32; i += 256) {
        int outr = i >> 5, outc = i & 31;
        int R = r0 + outr - 1;
        if ((unsigned)R < 32u)
            atomicAdd(&logits[n * 1024 + R * 32 + outc], s_log[i]);
    }
}

__global__ __launch_bounds__(256) void bce_reduce_kernel(
    const float* __restrict__ logits, const int* __restrict__ seg,
    const int* __restrict__ anchors, const int* __restrict__ labels,
    const int* __restrict__ base_classes, const float* __restrict__ b2,
    float* __restrict__ out)
{
    const int n = blockIdx.x;
    const int t = threadIdx.x;
    const int y0 = anchors[n * 4 + 2];
    const int x0 = anchors[n * 4 + 0];
    const int tgt_cls = base_classes[labels[n]];
    const float bias2 = b2[0];

    float lsum = 0.0f;
    #pragma unroll
    for (int r = 0; r < 4; ++r) {
        int p = t + r * 256;
        int i = p >> 5, j = p & 31;
        float l = logits[n * 1024 + p] + bias2;
        int sv = seg[(size_t)(4 * (y0 + i)) * IMGD + 4 * (x0 + j)];
        float tgt = (sv == tgt_cls) ? 1.0f : 0.0f;
        lsum += fmaxf(l, 0.0f) - l * tgt + log1pf(expf(-fabsf(l)));
    }
    #pragma unroll
    for (int off = 32; off > 0; off >>= 1) lsum += __shfl_down(lsum, off, 64);
    __shared__ float s[4];
    if ((t & 63) == 0) s[t >> 6] = lsum;
    __syncthreads();
    if (t == 0) {
        float tot = s[0] + s[1] + s[2] + s[3];
        const float scale = 1.0f / (1024.0f * (256.0f + 1e-10f));
        atomicAdd(out, tot * scale);
    }
}

extern "C" void kernel_launch(void* const* d_in, const int* in_sizes, int n_in,
                              void* d_out, int out_size, void* d_ws, size_t ws_size,
                              hipStream_t stream) {
    const float* fm           = (const float*)d_in[0];
    const int*   seg          = (const int*)d_in[1];
    const int*   anchors      = (const int*)d_in[2];
    const int*   labels       = (const int*)d_in[3];
    const int*   base_classes = (const int*)d_in[4];
    const float* W1           = (const float*)d_in[5];
    const float* b1           = (const float*)d_in[6];
    const float* W2           = (const float*)d_in[7];
    const float* b2           = (const float*)d_in[8];
    float* out = (float*)d_out;

    float*    logits = (float*)d_ws;
    uchar_t*  w1r    = (uchar_t*)((char*)d_ws + W1R_BYTE_OFF);
    ushort_t* w2r    = (ushort_t*)((char*)d_ws + W2R_BYTE_OFF);
    uchar_t*  fmT    = (uchar_t*)((char*)d_ws + FMT_BYTE_OFF);

    prep_misc<<<1024 + 128 + 1, 256, 0, stream>>>(W1, W2, logits, out, w1r, w2r);
    prep_transpose<<<dim3(10, 320), 256, 0, stream>>>(fm, fmT);
    conv_mfma_kernel<<<2048, 256, 0, stream>>>(fm, anchors, fmT, w1r, w2r, b1, logits);
    bce_reduce_kernel<<<NA, 256, 0, stream>>>(logits, seg, anchors, labels, base_classes, b2, out);
}

// Round 6
// 227.731 us; speedup vs baseline: 7.8993x; 1.4956x over previous
//
#include <hip/hip_runtime.h>

typedef __attribute__((ext_vector_type(8))) short short8;
typedef __attribute__((ext_vector_type(8))) int int8v;
typedef __attribute__((ext_vector_type(16))) float floatx16;
typedef __attribute__((ext_vector_type(4))) unsigned int uint4v;
typedef unsigned short ushort_t;
typedef unsigned int uint_t;
typedef unsigned char uchar_t;

#define NA   256
#define CIN  128
#define HFD  320
#define FMPX (HFD*HFD)
#define IMGD 1280

// ws layout (bytes):
//   [0, 1MB)              logits f32 (NA*1024)
//   [1MB, +294912)        w1r fp8  [9 tap][256 oc][128 cin], scaled x64
//   [+294912, +311296)    w2r bf16 [32 krow][256 oc]
//   [2MB, 2MB+13107200)   fmT fp8  [320 y][320 x][128 c]
#define W1R_BYTE_OFF (1u<<20)
#define W2R_BYTE_OFF ((1u<<20) + 9*256*128)
#define FMT_BYTE_OFF (2u<<20)

#define SAPL 9792                 // A sub-plane bytes: 612 padded cells * 16
#define SBPL 9216                 // B sub-plane bytes: 576 cells * 16
#define SA_BYTES (4*SAPL)         // 39168
#define SB_BYTES (4*SBPL)         // 36864
#define PSTR_H 8208               // bytes per oc-octet plane of s_h (16*32*16 + 16 pad)

union V32 { int8v v; uint4v q[2]; };

__device__ __forceinline__ ushort_t f2bf(float v) {
    uint_t u = __float_as_uint(v);
    return (ushort_t)((u + 0x8000u) >> 16);
}
__device__ __forceinline__ uchar_t f2fp8(float v) {
    int r = __builtin_amdgcn_cvt_pk_fp8_f32(v, 0.0f, 0, false);
    return (uchar_t)(r & 0xff);
}

__global__ __launch_bounds__(256) void prep_misc(
    const float* __restrict__ W1, const float* __restrict__ W2,
    float* __restrict__ logits, float* __restrict__ out,
    uchar_t* __restrict__ w1r, ushort_t* __restrict__ w2r)
{
    const int b = blockIdx.x, t = threadIdx.x;
    if (b < 1024) {
        logits[b * 256 + t] = 0.0f;
    } else if (b < 1024 + 128) {
        int e = (b - 1024) * 256 + t;
        int oc = e >> 7, cin = e & 127;
        #pragma unroll
        for (int tap = 0; tap < 9; ++tap)
            w1r[(tap * 256 + oc) * 128 + cin] = f2fp8(W1[(oc * 128 + cin) * 9 + tap] * 64.0f);
    } else {
        #pragma unroll
        for (int i = 0; i < 32; ++i) {
            int e = i * 256 + t;
            int nrow = e >> 8, oc = e & 255;
            w2r[nrow * 256 + oc] = f2bf(nrow < 9 ? W2[oc * 9 + nrow] : 0.0f);
        }
        if (t == 0) out[0] = 0.0f;
    }
}

// fm f32 [c][y][x] -> fmT fp8 [y][x][c]
__global__ __launch_bounds__(256) void prep_transpose(
    const float* __restrict__ fm, uchar_t* __restrict__ fmT)
{
    __shared__ uchar_t s[32 * 144];
    const int t = threadIdx.x;
    const int y = blockIdx.y, x0b = blockIdx.x * 32;
    #pragma unroll
    for (int i = 0; i < 16; ++i) {
        int e = t + 256 * i;
        int c = e >> 5, xo = e & 31;
        s[xo * 144 + c] = f2fp8(fm[(size_t)c * FMPX + y * HFD + x0b + xo]);
    }
    __syncthreads();
    {
        int xo = t >> 3, cg = t & 7;
        uint4v v = *(const uint4v*)&s[xo * 144 + cg * 16];
        *(uint4v*)&fmT[((size_t)(y * HFD + x0b + xo)) * 128 + cg * 16] = v;
    }
}

// Block = (anchor, 16-row half, 64-oc group); grid 2048, XCD-swizzled.
// K=64 fp8 via mfma_scale_f32_32x32x64_f8f6f4 with unity E8M0 scales (127) -> 2 cin-chunks.
// LDS sub-plane layout: 16-B unit `sub` of cell c lives at sub*PLANE + c*16 -> every frag
// read / staging store is lane-stride-16B contiguous (conflict-free optimal).
// No register prefetch (spill-safe): stage chunk -> barrier -> MFMA; one exposed stage mid-kernel.
// Epilogue: store relu(h)+bias for BOTH oc-halves (frees acc AGPRs), then v_tap = h @ W2^T (bf16),
// scatter-add via LDS then global atomics.
__global__ __launch_bounds__(256, 2) void conv_mfma_kernel(
    const int* __restrict__ anchors, const uchar_t* __restrict__ fmT,
    const uchar_t* __restrict__ w1r, const ushort_t* __restrict__ w2r,
    const float* __restrict__ b1, float* __restrict__ logits)
{
    const int id   = blockIdx.x;
    const int xcd  = id & 7, sid = id >> 3;
    const int n    = xcd * 32 + (sid >> 3);
    const int rem  = sid & 7;
    const int half = rem >> 2;
    const int g    = rem & 3;

    const int t    = threadIdx.x;
    const int w    = t >> 6;
    const int lane = t & 63;
    const int l31  = lane & 31;
    const int kh   = lane >> 5;

    const int x0 = anchors[n * 4 + 0];
    const int y0 = anchors[n * 4 + 2];
    const int r0 = half * 16;
    const int pro = 1 - half;            // pad-row offset of first real input row

    __shared__ __align__(16) char smem[SA_BYTES + SB_BYTES];   // 76032 B; union s_h (8*8208=65664)
    char* s_a = smem;
    char* s_b = smem + SA_BYTES;
    __shared__ float s_log[18 * 32];

    // zero A region once (col pads pc{0,33} and row pads are chunk-invariant)
    for (int i = t; i < SA_BYTES / 4; i += 256) ((uint_t*)s_a)[i] = 0u;

    floatx16 acc[4][2];
    #pragma unroll
    for (int mt = 0; mt < 4; ++mt)
        #pragma unroll
        for (int nt = 0; nt < 2; ++nt)
            #pragma unroll
            for (int r = 0; r < 16; ++r) acc[mt][nt][r] = 0.0f;

    for (int c = 0; c < 2; ++c) {
        const int cb = c * 64;
        __syncthreads();   // c0: zero-fill visible; c1: all waves done reading chunk0
        // ---- stage A: 544 real cells (17 rows x 32 cols) x 4 subs = 2176 uint4 units ----
        #pragma unroll
        for (int j = 0; j < 9; ++j) {
            int u = t + 256 * j;
            if (j < 8 || u < 2176) {
                int cell = u >> 2, sub = u & 3;
                int ri = cell >> 5, col = cell & 31;
                int pr = ri + pro, cr = r0 + pr - 1;
                uint4v v = *(const uint4v*)&fmT[((size_t)((y0 + cr) * HFD + x0 + col)) * 128 + cb + sub * 16];
                *(uint4v*)(s_a + sub * SAPL + (pr * 34 + col + 1) * 16) = v;
            }
        }
        // ---- stage B: 576 cells (9 tap x 64 oc) x 4 subs = 2304 units ----
        #pragma unroll
        for (int j = 0; j < 9; ++j) {
            int u = t + 256 * j;
            int cell = u >> 2, sub = u & 3;
            int tap = cell >> 6, oc = cell & 63;
            uint4v v = *(const uint4v*)&w1r[(size_t)((tap * 256 + g * 64 + oc) * 128) + cb + sub * 16];
            *(uint4v*)(s_b + sub * SBPL + cell * 16) = v;
        }
        __syncthreads();
        // ---- MFMA: per kx, 6 A-frags (ky-shared) + per ky 2 B-frags -> 8 MFMAs ----
        #pragma unroll
        for (int kx = 0; kx < 3; ++kx) {
            V32 a8[6];
            #pragma unroll
            for (int r = 0; r < 6; ++r) {
                int cell = (4 * w + r) * 34 + l31 + kx;
                a8[r].q[0] = *(const uint4v*)(s_a + (2 * kh)     * SAPL + cell * 16);
                a8[r].q[1] = *(const uint4v*)(s_a + (2 * kh + 1) * SAPL + cell * 16);
            }
            #pragma unroll
            for (int ky = 0; ky < 3; ++ky) {
                int tap = ky * 3 + kx;
                V32 b8[2];
                #pragma unroll
                for (int nt = 0; nt < 2; ++nt) {
                    int cell = tap * 64 + nt * 32 + l31;
                    b8[nt].q[0] = *(const uint4v*)(s_b + (2 * kh)     * SBPL + cell * 16);
                    b8[nt].q[1] = *(const uint4v*)(s_b + (2 * kh + 1) * SBPL + cell * 16);
                }
                #pragma unroll
                for (int mt = 0; mt < 4; ++mt) {
                    acc[mt][0] = __builtin_amdgcn_mfma_scale_f32_32x32x64_f8f6f4(
                        a8[mt + ky].v, b8[0].v, acc[mt][0], 0, 0, 0, 127, 0, 127);
                    acc[mt][1] = __builtin_amdgcn_mfma_scale_f32_32x32x64_f8f6f4(
                        a8[mt + ky].v, b8[1].v, acc[mt][1], 0, 0, 0, 127, 0, 127);
                }
            }
        }
    }

    // ---- epilogue: h = acc/64 + b1, relu -> s_h for BOTH oc-halves (acc freed after) ----
    __syncthreads();
    #pragma unroll
    for (int pass = 0; pass < 2; ++pass) {
        float bias = b1[g * 64 + pass * 32 + l31];
        int plane = pass * 4 + (l31 >> 3);
        #pragma unroll
        for (int mt = 0; mt < 4; ++mt) {
            int lr = 4 * w + mt;
            #pragma unroll
            for (int reg = 0; reg < 16; ++reg) {
                int col = (reg & 3) + 8 * (reg >> 2) + 4 * kh;   // C: m = crop col
                float hv = fmaxf(fmaf(acc[mt][pass][reg], 0.015625f, bias), 0.0f);
                *(ushort_t*)(smem + plane * PSTR_H + ((lr * 32 + col) * 8 + (l31 & 7)) * 2) = f2bf(hv);
            }
        }
    }
    __syncthreads();

    // ---- v_tap = h @ W2^T (bf16, K=64 oc over 4 x K16) ----
    floatx16 vacc[4];
    #pragma unroll
    for (int mt = 0; mt < 4; ++mt)
        #pragma unroll
        for (int r = 0; r < 16; ++r) vacc[mt][r] = 0.0f;
    #pragma unroll
    for (int ks = 0; ks < 4; ++ks) {
        short8 bw = *(const short8*)&w2r[l31 * 256 + g * 64 + ks * 16 + kh * 8];
        #pragma unroll
        for (int mt = 0; mt < 4; ++mt) {
            short8 ah = *(const short8*)(smem + (ks * 2 + kh) * PSTR_H + ((4 * w + mt) * 32 + l31) * 16);
            vacc[mt] = __builtin_amdgcn_mfma_f32_32x32x16_bf16(ah, bw, vacc[mt], 0, 0, 0);
        }
    }

    // ---- scatter v_tap into 18x32 tile, then global atomics ----
    __syncthreads();
    for (int i = t; i < 18 * 32; i += 256) s_log[i] = 0.0f;
    __syncthreads();
    if (l31 < 9) {
        int ky = l31 / 3, kx = l31 - ky * 3;
        #pragma unroll
        for (int mt = 0; mt < 4; ++mt) {
            int outr = 4 * w + mt + 2 - ky;       // tile row; R = r0 + outr - 1
            #pragma unroll
            for (int reg = 0; reg < 16; ++reg) {
                int col  = (reg & 3) + 8 * (reg >> 2) + 4 * kh;
                int outc = col + 1 - kx;
                if (outc >= 0 && outc < 32)
                    atomicAdd(&s_log[outr * 32 + outc], vacc[mt][reg]);
            }
        }
    }
    __syncthreads();
    for (int i = t; i < 18 * 32; i += 256) {
        int outr = i >> 5, outc = i & 31;
        int R = r0 + outr - 1;
        if ((unsigned)R < 32u)
            atomicAdd(&logits[n * 1024 + R * 32 + outc], s_log[i]);
    }
}

__global__ __launch_bounds__(256) void bce_reduce_kernel(
    const float* __restrict__ logits, const int* __restrict__ seg,
    const int* __restrict__ anchors, const int* __restrict__ labels,
    const int* __restrict__ base_classes, const float* __restrict__ b2,
    float* __restrict__ out)
{
    const int n = blockIdx.x;
    const int t = threadIdx.x;
    const int y0 = anchors[n * 4 + 2];
    const int x0 = anchors[n * 4 + 0];
    const int tgt_cls = base_classes[labels[n]];
    const float bias2 = b2[0];

    float lsum = 0.0f;
    #pragma unroll
    for (int r = 0; r < 4; ++r) {
        int p = t + r * 256;
        int i = p >> 5, j = p & 31;
        float l = logits[n * 1024 + p] + bias2;
        int sv = seg[(size_t)(4 * (y0 + i)) * IMGD + 4 * (x0 + j)];
        float tgt = (sv == tgt_cls) ? 1.0f : 0.0f;
        lsum += fmaxf(l, 0.0f) - l * tgt + log1pf(expf(-fabsf(l)));
    }
    #pragma unroll
    for (int off = 32; off > 0; off >>= 1) lsum += __shfl_down(lsum, off, 64);
    __shared__ float s[4];
    if ((t & 63) == 0) s[t >> 6] = lsum;
    __syncthreads();
    if (t == 0) {
        float tot = s[0] + s[1] + s[2] + s[3];
        const float scale = 1.0f / (1024.0f * (256.0f + 1e-10f));
        atomicAdd(out, tot * scale);
    }
}

extern "C" void kernel_launch(void* const* d_in, const int* in_sizes, int n_in,
                              void* d_out, int out_size, void* d_ws, size_t ws_size,
                              hipStream_t stream) {
    const float* fm           = (const float*)d_in[0];
    const int*   seg          = (const int*)d_in[1];
    const int*   anchors      = (const int*)d_in[2];
    const int*   labels       = (const int*)d_in[3];
    const int*   base_classes = (const int*)d_in[4];
    const float* W1           = (const float*)d_in[5];
    const float* b1           = (const float*)d_in[6];
    const float* W2           = (const float*)d_in[7];
    const float* b2           = (const float*)d_in[8];
    float* out = (float*)d_out;

    float*    logits = (float*)d_ws;
    uchar_t*  w1r    = (uchar_t*)((char*)d_ws + W1R_BYTE_OFF);
    ushort_t* w2r    = (ushort_t*)((char*)d_ws + W2R_BYTE_OFF);
    uchar_t*  fmT    = (uchar_t*)((char*)d_ws + FMT_BYTE_OFF);

    prep_misc<<<1024 + 128 + 1, 256, 0, stream>>>(W1, W2, logits, out, w1r, w2r);
    prep_transpose<<<dim3(10, 320), 256, 0, stream>>>(fm, fmT);
    conv_mfma_kernel<<<2048, 256, 0, stream>>>(anchors, fmT, w1r, w2r, b1, logits);
    bce_reduce_kernel<<<NA, 256, 0, stream>>>(logits, seg, anchors, labels, base_classes, b2, out);
}